// Round 2
// 675.114 us; speedup vs baseline: 1.0377x; 1.0377x over previous
//
#include <hip/hip_runtime.h>

typedef unsigned short u16;
typedef __bf16 bfv8 __attribute__((ext_vector_type(8)));
typedef float f32x4 __attribute__((ext_vector_type(4)));
typedef u16 u16x8 __attribute__((ext_vector_type(8)));

#define B_      2
#define T_      2048
#define C_      2048
#define H_      16
#define HD_     128
#define NT_     (B_ * T_)
#define DOWN_N  1088
#define DCAT    1168   // 1088 (down) + 80 (gate logits)
#define DCATP   1280   // DCAT padded to 128 multiple (zero rows) for gload_lds GEMM
#define KV_N    3072
#define Q_N     2048
#define EPS_    1.1920929e-07f
// softmax scale (1/sqrt(128)) * log2(e), for exp2-domain online softmax
#define CEXP    0.12751879524580262f

__device__ __forceinline__ float b2f(u16 u) {
    union { unsigned u; float f; } c; c.u = ((unsigned)u) << 16; return c.f;
}
__device__ __forceinline__ u16 f2b(float f) {
    union { float f; unsigned u; } c; c.f = f;
    return (u16)((c.u + 0x7FFFu + ((c.u >> 16) & 1u)) >> 16);
}
__device__ __forceinline__ float dynload(const void* p, size_t i, int bf) {
    if (bf) return b2f(((const u16*)p)[i]);
    return ((const float*)p)[i];
}

// async global->LDS, 16B per lane (wave-uniform LDS base + lane*16)
__device__ __forceinline__ void gload16(const u16* g, u16* l) {
    __builtin_amdgcn_global_load_lds(
        (const __attribute__((address_space(1))) void*)g,
        (__attribute__((address_space(3))) void*)l,
        16, 0, 0);
}

// ---------------------------------------------------------------------------
// Input dtype detector (writes flag[0] = 1 if bf16).
// ---------------------------------------------------------------------------
__global__ void detect_kernel(const unsigned* __restrict__ x, int* __restrict__ flag) {
    __shared__ int cnt;
    if (threadIdx.x == 0) cnt = 0;
    __syncthreads();
    int c = 0;
    for (int i = threadIdx.x; i < 4096; i += 256) {
        const unsigned w = x[i];
        const unsigned e = (w >> 7) & 0xFF;
        if (e >= 105 && e <= 140) ++c;
    }
    atomicAdd(&cnt, c);
    __syncthreads();
    if (threadIdx.x == 0) flag[0] = (cnt > 2300) ? 1 : 0;
}

// ---------------------------------------------------------------------------
// Elementwise cast (dyn f32/bf16 -> bf16), 8 elems/thread.
// ---------------------------------------------------------------------------
__global__ __launch_bounds__(256) void cast_kernel(
    const void* __restrict__ in, u16* __restrict__ out, int n, const int* __restrict__ flagp)
{
    const int fl = flagp[0];
    const int i0 = (blockIdx.x * 256 + threadIdx.x) * 8;
    if (i0 + 8 > n) return;
    u16x8 o;
    #pragma unroll
    for (int i = 0; i < 8; ++i) o[i] = f2b(dynload(in, (size_t)i0 + i, fl));
    *(u16x8*)(out + i0) = o;
}

// ---------------------------------------------------------------------------
// Transpose + cast: W[K][N] (dyn) -> W_T[N][K] (bf16). 32x32 LDS tiles.
// Rows [N, Ntot) are written as zeros (pad for gload_lds GEMM B-tiles).
// ---------------------------------------------------------------------------
__global__ __launch_bounds__(256) void tcast_kernel(
    const void* __restrict__ in, u16* __restrict__ out, int K, int N, int Ntot,
    const int* __restrict__ flagp)
{
    const int fl = flagp[0];
    __shared__ float sf[32][33];
    const int n0 = blockIdx.x * 32, k0 = blockIdx.y * 32;
    const int tx = threadIdx.x & 31, ty = threadIdx.x >> 5;
    const int cr = (n0 + tx < N) ? (n0 + tx) : (N - 1);   // clamped read col
    #pragma unroll
    for (int i = 0; i < 4; ++i)
        sf[ty + 8 * i][tx] = dynload(in, (size_t)(k0 + ty + 8 * i) * N + cr, fl);
    __syncthreads();
    #pragma unroll
    for (int i = 0; i < 4; ++i) {
        const int n = n0 + ty + 8 * i;
        if (n < Ntot) out[(size_t)n * K + k0 + tx] = (n < N) ? f2b(sf[tx][ty + 8 * i]) : (u16)0;
    }
}

// ---------------------------------------------------------------------------
// MFMA GEMM (m97 structure): C[M,N] = A[M,K] @ B[K,N], A row-major bf16,
// BT = B^T row-major bf16 [N][K] (rows padded so n-tiles are full 128).
// 128x128 tile, BK=32, 4 waves each 64x64 (4x4 of 16x16x32).
// Staging via global_load_lds width=16 into LINEAR (unpadded) LDS:
// wave w stages rows [w*32, w*32+32) of both A and B tiles; lane l covers
// row w*32+i*16+(l>>2), col (l&3)*8 u16 == LDS base + 16B*l.
// ---------------------------------------------------------------------------
__device__ __forceinline__ void stc(u16* p, float v)  { *p = f2b(v); }
__device__ __forceinline__ void stc(float* p, float v){ *p = v; }

template <typename TC>
__global__ __launch_bounds__(256) void mfma_gemm(
    const u16* __restrict__ A, int lda,
    const u16* __restrict__ BT, int ldb,
    TC* __restrict__ Cm, int ldc,
    int M, int N, int K)
{
    __shared__ u16 As[128 * 32];   // linear [m][k], row = 64B
    __shared__ u16 Bs[128 * 32];   // linear [n][k]
    const int tid = threadIdx.x;
    const int m0 = blockIdx.y * 128, n0 = blockIdx.x * 128;
    const int w = tid >> 6, l = tid & 63;
    const int wm = (w >> 1) * 64, wn = (w & 1) * 64;
    const int lr = l & 15, lq = l >> 4;

    f32x4 acc[4][4];
    #pragma unroll
    for (int i = 0; i < 4; ++i)
        #pragma unroll
        for (int j = 0; j < 4; ++j) acc[i][j] = (f32x4){0.f, 0.f, 0.f, 0.f};

    // per-lane global source addresses matching the linear LDS order
    const int srow = w * 32 + (l >> 2);
    const int scol = (l & 3) * 8;
    const u16* ag = A  + (size_t)(m0 + srow) * lda + scol;
    const u16* bg = BT + (size_t)(n0 + srow) * ldb + scol;
    u16* as0 = &As[(w * 32) * 32];
    u16* as1 = &As[(w * 32 + 16) * 32];
    u16* bs0 = &Bs[(w * 32) * 32];
    u16* bs1 = &Bs[(w * 32 + 16) * 32];

    for (int k0 = 0; k0 < K; k0 += 32) {
        gload16(ag + k0,            as0);
        gload16(ag + 16 * lda + k0, as1);
        gload16(bg + k0,            bs0);
        gload16(bg + 16 * ldb + k0, bs1);
        __syncthreads();
        bfv8 af[4], bf[4];
        #pragma unroll
        for (int mi = 0; mi < 4; ++mi) af[mi] = *(const bfv8*)&As[(wm + mi * 16 + lr) * 32 + lq * 8];
        #pragma unroll
        for (int ni = 0; ni < 4; ++ni) bf[ni] = *(const bfv8*)&Bs[(wn + ni * 16 + lr) * 32 + lq * 8];
        #pragma unroll
        for (int mi = 0; mi < 4; ++mi)
            #pragma unroll
            for (int ni = 0; ni < 4; ++ni)
                acc[mi][ni] = __builtin_amdgcn_mfma_f32_16x16x32_bf16(af[mi], bf[ni], acc[mi][ni], 0, 0, 0);
        __syncthreads();
    }

    #pragma unroll
    for (int mi = 0; mi < 4; ++mi) {
        #pragma unroll
        for (int ni = 0; ni < 4; ++ni) {
            const int col = n0 + wn + ni * 16 + lr;
            if (col < N) {
                #pragma unroll
                for (int r = 0; r < 4; ++r) {
                    const int row = m0 + wm + mi * 16 + lq * 4 + r;
                    stc(&Cm[(size_t)row * ldc + col], acc[mi][ni][r]);
                }
            }
        }
    }
}

// ---------------------------------------------------------------------------
// Assemble q/k/v per (b,t): rope + rmsnorm for q,k; gated v with ve einsum.
// Gate logits come from down cols 1088..1167 (fused into down GEMM).
// ---------------------------------------------------------------------------
__global__ __launch_bounds__(256) void assemble_kernel(
    const u16* __restrict__ down,      // [NT,1168] bf16
    const u16* __restrict__ qraw,      // [NT,2048] bf16
    const u16* __restrict__ kv,        // [NT,3072] bf16
    const void* __restrict__ ve,       // [NT,8192] dyn
    const void* __restrict__ cosg,     // [NT,32]   dyn
    const void* __restrict__ sing,     // [NT,32]   dyn
    u16* __restrict__ qo, u16* __restrict__ ko, u16* __restrict__ vo,
    const int* __restrict__ flagp)
{
    const int fl = flagp[0];
    const int bt = blockIdx.x;
    const int tid = threadIdx.x;
    __shared__ float cs[32], sn[32], kr[64];
    if (tid < 32) {
        cs[tid] = dynload(cosg, (size_t)bt * 32 + tid, fl);
        sn[tid] = dynload(sing, (size_t)bt * 32 + tid, fl);
    }
    __syncthreads();
    if (tid < 64) {
        const u16* rp = down + (size_t)bt * DCAT + 1024;
        const int d = tid;
        if (d < 32) kr[d] = b2f(rp[d]) * cs[d] + b2f(rp[d + 32]) * sn[d];
        else { const int r = d - 32; kr[d] = -b2f(rp[d - 32]) * sn[r] + b2f(rp[d]) * cs[r]; }
    }
    __syncthreads();

    const int h = tid >> 4;
    const int lane = tid & 15;
    const int d0 = lane * 8;

    // Q: rope on [64,128), rmsnorm over 128
    const u16* qr = qraw + (size_t)bt * Q_N + h * HD_;
    float vq[8];
    float ss = 0.f;
    #pragma unroll
    for (int i = 0; i < 8; ++i) {
        const int d = d0 + i;
        float xv = b2f(qr[d]);
        if (d >= 64) {
            if (d < 96) { const int r = d - 64; xv = xv * cs[r] + b2f(qr[d + 32]) * sn[r]; }
            else        { const int r = d - 96; xv = -b2f(qr[d - 32]) * sn[r] + xv * cs[r]; }
        }
        vq[i] = xv; ss += xv * xv;
    }
    #pragma unroll
    for (int off = 1; off < 16; off <<= 1) ss += __shfl_xor(ss, off);
    float rms = rsqrtf(ss * (1.f / 128.f) + EPS_);
    u16* qop = qo + (size_t)bt * Q_N + h * HD_ + d0;
    #pragma unroll
    for (int i = 0; i < 8; ++i) qop[i] = f2b(vq[i] * rms);

    // K: [k_nope(64) | roped k_rope(64)], rmsnorm over 128
    const u16* kvp = kv + (size_t)bt * KV_N + h * 192;
    float vk[8];
    ss = 0.f;
    #pragma unroll
    for (int i = 0; i < 8; ++i) {
        const int d = d0 + i;
        const float xv = (d < 64) ? b2f(kvp[d]) : kr[d - 64];
        vk[i] = xv; ss += xv * xv;
    }
    #pragma unroll
    for (int off = 1; off < 16; off <<= 1) ss += __shfl_xor(ss, off);
    rms = rsqrtf(ss * (1.f / 128.f) + EPS_);
    u16* kop = ko + (size_t)bt * Q_N + h * HD_ + d0;
    #pragma unroll
    for (int i = 0; i < 8; ++i) kop[i] = f2b(vk[i] * rms);

    // V: g0 * v + sum_m g[m+1] * ve[m]; gates = 2*sigmoid(down[1088 + h*5 + j])
    float g[5];
    #pragma unroll
    for (int j = 0; j < 5; ++j) {
        const float logit = b2f(down[(size_t)bt * DCAT + 1088 + h * 5 + j]);
        g[j] = 2.f / (1.f + expf(-logit));
    }
    const u16* vp = kvp + 64;
    const size_t vebase = (size_t)bt * 8192 + h * HD_;
    u16* vop = vo + (size_t)bt * Q_N + h * HD_ + d0;
    #pragma unroll
    for (int i = 0; i < 8; ++i) {
        const int d = d0 + i;
        float val = g[0] * b2f(vp[d]);
        #pragma unroll
        for (int m = 0; m < 4; ++m) val += g[1 + m] * dynload(ve, vebase + m * 2048 + d, fl);
        vop[i] = f2b(val);
    }
}

// ---------------------------------------------------------------------------
// V transpose: vn [b][t][h][d] -> vt [(b,h)][d][t]   (bf16, 64x64 tiles)
// ---------------------------------------------------------------------------
__global__ __launch_bounds__(256) void vtrans_kernel(
    const u16* __restrict__ vn, u16* __restrict__ vt)
{
    __shared__ u16 s[64][72];
    const int t0 = blockIdx.x * 64;
    const int d0 = blockIdx.y * 64;
    const int bh = blockIdx.z;
    const int tid = threadIdx.x;
    {
        const int tt = tid >> 2, seg = tid & 3;
        const u16* p = vn + ((size_t)((bh >> 4) * T_) + t0 + tt) * 2048 + (bh & 15) * 128 + d0 + seg * 16;
        u16x8 v0 = *(const u16x8*)(p);
        u16x8 v1 = *(const u16x8*)(p + 8);
        *(u16x8*)&s[tt][seg * 16]     = v0;
        *(u16x8*)&s[tt][seg * 16 + 8] = v1;
    }
    __syncthreads();
    {
        const int dd = tid >> 2, tseg = tid & 3;
        u16* q = vt + ((size_t)(bh * 128) + d0 + dd) * T_ + t0 + tseg * 16;
        #pragma unroll
        for (int g = 0; g < 2; ++g) {
            u16x8 o;
            #pragma unroll
            for (int i = 0; i < 8; ++i) o[i] = s[tseg * 16 + g * 8 + i][dd];
            *(u16x8*)(q + g * 8) = o;
        }
    }
}

// ---------------------------------------------------------------------------
// MFMA flash attention. Block = 512 threads (8 waves), 128 Q rows.
// 64-key tiles; each wave owns 16 Q rows. Online softmax in registers.
//
// Load balance: causal work per m-block is 2*mb+2 tiles. Under XCD
// round-robin (bid%8 -> XCD) the co-resident CU pair is (bid, bid+256)
// which differ only in b -> identical work, and XCD x only sees
// mb in {x, x+8} -> 2.4x XCD imbalance. Remap mb = b ? 15-bx : bx makes
// every co-resident pair sum to exactly 34 tile-units and every XCD equal.
//
// T14 async-STAGE: issue next tile's K/V global loads into registers before
// compute; LDS write happens next iteration after barrier, hiding HBM
// latency under QK/softmax/PV.
// ---------------------------------------------------------------------------
__global__ __launch_bounds__(512) void attn_mfma(
    const u16* __restrict__ qn, const u16* __restrict__ kn,
    const u16* __restrict__ vt, u16* __restrict__ yb,
    const int* __restrict__ wptr)
{
    __shared__ u16 Ks[64][136];      // K tile row-major [key][d]
    __shared__ u16 VTs[128][72];     // V tile transposed [d][key]
    __shared__ u16 Ps[8][16][72];    // per-wave P round-trip [qrow][key]

    const int h = blockIdx.y, b = blockIdx.z;
    const int mb = b ? ((int)gridDim.x - 1 - (int)blockIdx.x) : (int)blockIdx.x;
    const int m0 = mb * 128;
    const int W = wptr[0];
    const int tid = threadIdx.x;
    const int w = tid >> 6, l = tid & 63;
    const int lr = l & 15, lq = l >> 4;
    const int qr0 = m0 + w * 16;

    bfv8 qf[4];
    {
        const u16* qp = qn + ((size_t)(b * T_) + qr0 + lr) * 2048 + h * 128 + lq * 8;
        #pragma unroll
        for (int kk = 0; kk < 4; ++kk) qf[kk] = *(const bfv8*)(qp + kk * 32);
    }

    f32x4 oacc[8];
    #pragma unroll
    for (int i = 0; i < 8; ++i) oacc[i] = (f32x4){0.f, 0.f, 0.f, 0.f};
    float m_r[4] = {-1e30f, -1e30f, -1e30f, -1e30f};
    float l_r[4] = {0.f, 0.f, 0.f, 0.f};

    const int kkey = tid >> 3, kseg = tid & 7;   // K staging: 64 keys x 8 segs of 16
    const int vd = tid >> 2, vh = tid & 3;       // V staging: 128 d x 4 segs of 16

    int ns = m0 - W; if (ns < 0) ns = 0; ns &= ~63;
    const int ne = m0 + 64;                      // inclusive last tile start

    const u16* kbase = kn + ((size_t)(b * T_) + kkey) * 2048 + h * 128 + kseg * 16;
    const u16* vbase = vt + ((size_t)(b * H_ + h) * 128 + vd) * T_ + vh * 16;

    // prologue: prefetch first tile into registers
    u16x8 pk0, pk1, pv0, pv1;
    {
        const u16* kp = kbase + (size_t)ns * 2048;
        const u16* vp = vbase + ns;
        pk0 = *(const u16x8*)(kp);
        pk1 = *(const u16x8*)(kp + 8);
        pv0 = *(const u16x8*)(vp);
        pv1 = *(const u16x8*)(vp + 8);
    }

    for (int n0 = ns; n0 <= ne; n0 += 64) {
        // write previously-fetched tile to LDS (prev compute done: trailing barrier)
        *(u16x8*)&Ks[kkey][kseg * 16]     = pk0;
        *(u16x8*)&Ks[kkey][kseg * 16 + 8] = pk1;
        *(u16x8*)&VTs[vd][vh * 16]        = pv0;
        *(u16x8*)&VTs[vd][vh * 16 + 8]    = pv1;
        __syncthreads();

        // issue next tile's loads now; latency hides under compute below
        if (n0 < ne) {
            const u16* kp = kbase + (size_t)(n0 + 64) * 2048;
            const u16* vp = vbase + (n0 + 64);
            pk0 = *(const u16x8*)(kp);
            pk1 = *(const u16x8*)(kp + 8);
            pv0 = *(const u16x8*)(vp);
            pv1 = *(const u16x8*)(vp + 8);
        }

        // per-wave early-out on fully-masked tiles (barriers stay uniform)
        const bool active = (n0 <= qr0 + 15) && (n0 + 63 >= qr0 - W);
        if (active) {
            // S = Q K^T
            f32x4 s[4];
            #pragma unroll
            for (int f = 0; f < 4; ++f) {
                s[f] = (f32x4){0.f, 0.f, 0.f, 0.f};
                #pragma unroll
                for (int kk = 0; kk < 4; ++kk) {
                    bfv8 kf = *(const bfv8*)&Ks[f * 16 + lr][kk * 32 + lq * 8];
                    s[f] = __builtin_amdgcn_mfma_f32_16x16x32_bf16(qf[kk], kf, s[f], 0, 0, 0);
                }
            }

            if ((n0 + 63 > qr0) || (qr0 + 15 - n0 > W)) {
                #pragma unroll
                for (int f = 0; f < 4; ++f) {
                    const int si = n0 + f * 16 + lr;
                    #pragma unroll
                    for (int r = 0; r < 4; ++r) {
                        const int ti = qr0 + lq * 4 + r;
                        if (si > ti || ti - si > W) s[f][r] = -1e30f;
                    }
                }
            }

            // online softmax (rows in 16-lane groups)
            float al_r[4];
            #pragma unroll
            for (int r = 0; r < 4; ++r) {
                float mx = fmaxf(fmaxf(s[0][r], s[1][r]), fmaxf(s[2][r], s[3][r]));
                mx = fmaxf(mx, __shfl_xor(mx, 1));
                mx = fmaxf(mx, __shfl_xor(mx, 2));
                mx = fmaxf(mx, __shfl_xor(mx, 4));
                mx = fmaxf(mx, __shfl_xor(mx, 8));
                const float mnew = fmaxf(m_r[r], mx);
                al_r[r] = exp2f((m_r[r] - mnew) * CEXP);
                float ps = 0.f;
                #pragma unroll
                for (int f = 0; f < 4; ++f) {
                    const float sv = s[f][r];
                    const float pv = (sv <= -0.9e30f) ? 0.f : exp2f((sv - mnew) * CEXP);
                    s[f][r] = pv; ps += pv;
                }
                ps += __shfl_xor(ps, 1);
                ps += __shfl_xor(ps, 2);
                ps += __shfl_xor(ps, 4);
                ps += __shfl_xor(ps, 8);
                l_r[r] = l_r[r] * al_r[r] + ps;
                m_r[r] = mnew;
            }
            #pragma unroll
            for (int od = 0; od < 8; ++od)
                #pragma unroll
                for (int r = 0; r < 4; ++r) oacc[od][r] *= al_r[r];

            // P -> LDS (C-layout scatter); Ps[w] is wave-private, no barrier
            #pragma unroll
            for (int f = 0; f < 4; ++f)
                #pragma unroll
                for (int r = 0; r < 4; ++r)
                    Ps[w][lq * 4 + r][f * 16 + lr] = f2b(s[f][r]);

            // O += P V
            #pragma unroll
            for (int kk2 = 0; kk2 < 2; ++kk2) {
                bfv8 pf = *(const bfv8*)&Ps[w][lr][kk2 * 32 + lq * 8];
                #pragma unroll
                for (int od = 0; od < 8; ++od) {
                    bfv8 vf = *(const bfv8*)&VTs[od * 16 + lr][kk2 * 32 + lq * 8];
                    oacc[od] = __builtin_amdgcn_mfma_f32_16x16x32_bf16(pf, vf, oacc[od], 0, 0, 0);
                }
            }
        }
        __syncthreads();
    }

    float inv[4];
    #pragma unroll
    for (int r = 0; r < 4; ++r) inv[r] = 1.f / l_r[r];
    #pragma unroll
    for (int od = 0; od < 8; ++od)
        #pragma unroll
        for (int r = 0; r < 4; ++r) {
            const size_t idx = ((size_t)(b * T_) + qr0 + lq * 4 + r) * 2048 + h * 128 + od * 16 + lr;
            yb[idx] = f2b(oacc[od][r] * inv[r]);
        }
}

// ---------------------------------------------------------------------------
extern "C" void kernel_launch(void* const* d_in, const int* in_sizes, int n_in,
                              void* d_out, int out_size, void* d_ws, size_t ws_size,
                              hipStream_t stream)
{
    const void* x      = d_in[0];
    const void* ve     = d_in[1];
    const void* cosg   = d_in[2];
    const void* sing   = d_in[3];
    const void* w_down = d_in[4];
    const void* w_ukv  = d_in[5];
    const void* w_uq   = d_in[6];
    const void* w_gate = d_in[7];
    const void* w_proj = d_in[8];
    const int*  wsz    = (const int*)d_in[9];
    float* out = (float*)d_out;

    // workspace (~121 MB with aliasing)
    char* p = (char*)d_ws;
    u16* xbf    = (u16*)p; p += (size_t)NT_ * C_ * 2;          // reused as qn
    u16* wcatT  = (u16*)p; p += (size_t)DCATP * C_ * 2;        // [w_down|w_gate|0pad]^T
    u16* wukvT  = (u16*)p; p += (size_t)KV_N * 512 * 2;
    u16* wuqT   = (u16*)p; p += (size_t)Q_N * 512 * 2;
    u16* wpT    = (u16*)p; p += (size_t)C_ * C_ * 2;
    u16* downb  = (u16*)p; p += (size_t)NT_ * DCAT * 2;
    u16* kvb    = (u16*)p; p += (size_t)NT_ * KV_N * 2;
    u16* qraw   = (u16*)p; p += (size_t)NT_ * Q_N * 2;         // reused as vtb
    u16* kn     = (u16*)p; p += (size_t)NT_ * Q_N * 2;
    u16* vn     = (u16*)p; p += (size_t)NT_ * Q_N * 2;         // reused as ybf
    int* flag   = (int*)p; p += 256;
    u16* qn  = xbf;    // x_bf dead after down GEMM
    u16* vtb = qraw;   // qraw dead after assemble
    u16* ybf = vn;     // vn dead after vtrans (attn reads vtb)

    dim3 blk(256);
    detect_kernel<<<1, blk, 0, stream>>>((const unsigned*)x, flag);
    cast_kernel<<<dim3(NT_ * C_ / (256 * 8)), blk, 0, stream>>>(x, xbf, NT_ * C_, flag);
    tcast_kernel<<<dim3(DOWN_N / 32, C_ / 32), blk, 0, stream>>>(w_down, wcatT, C_, DOWN_N, DOWN_N, flag);
    // gate cols + zero-pad rows up to DCATP (192 rows total from offset 1088)
    tcast_kernel<<<dim3((DCATP - DOWN_N) / 32, C_ / 32), blk, 0, stream>>>(
        w_gate, wcatT + (size_t)DOWN_N * C_, C_, 80, DCATP - DOWN_N, flag);
    tcast_kernel<<<dim3(KV_N / 32, 512 / 32), blk, 0, stream>>>(w_ukv, wukvT, 512, KV_N, KV_N, flag);
    tcast_kernel<<<dim3(Q_N / 32, 512 / 32), blk, 0, stream>>>(w_uq, wuqT, 512, Q_N, Q_N, flag);
    tcast_kernel<<<dim3(C_ / 32, C_ / 32), blk, 0, stream>>>(w_proj, wpT, C_, C_, C_, flag);

    // down+gates = x @ [w_down|w_gate] -> bf16 [4096,1168] (B padded to 1280 rows)
    mfma_gemm<u16><<<dim3(DCATP / 128, NT_ / 128), blk, 0, stream>>>(
        xbf, C_, wcatT, C_, downb, DCAT, NT_, DCAT, C_);
    // kv = c_kv @ w_ukv -> bf16 [4096,3072]
    mfma_gemm<u16><<<dim3(KV_N / 128, NT_ / 128), blk, 0, stream>>>(
        downb, DCAT, wukvT, 512, kvb, KV_N, NT_, KV_N, 512);
    // q_raw = c_q @ w_uq -> bf16 [4096,2048]
    mfma_gemm<u16><<<dim3(Q_N / 128, NT_ / 128), blk, 0, stream>>>(
        downb + 512, DCAT, wuqT, 512, qraw, Q_N, NT_, Q_N, 512);
    // assemble q/k/v (incl. gate sigmoid from down logits)
    assemble_kernel<<<dim3(NT_), blk, 0, stream>>>(
        downb, qraw, kvb, ve, cosg, sing, qn, kn, vn, flag);
    // v transpose to [(b,h)][d][t]
    vtrans_kernel<<<dim3(T_ / 64, 2, B_ * H_), blk, 0, stream>>>(vn, vtb);
    // flash attention -> y bf16
    attn_mfma<<<dim3(T_ / 128, H_, B_), dim3(512), 0, stream>>>(qn, kn, vtb, ybf, wsz);
    // out = y @ w_proj -> f32
    mfma_gemm<float><<<dim3(Q_N / 128, NT_ / 128), blk, 0, stream>>>(
        ybf, Q_N, wpT, C_, out, C_, NT_, C_, Q_N);
}